// Round 6
// baseline (147.731 us; speedup 1.0000x reference)
//
#include <hip/hip_runtime.h>

// SEIR SDE: B=32768 trajectories, 1000 steps, batch-uniform noise.
// Output [step][4][B] f32 = 524 MB -> pure-write floor ~76-83 us.
// R1-R5 history: 242 -> 115.6 (unroll/store-rotation) -> ~110 plateau.
// R3/R5 falsified prefetch-depth and store-window theories. Remaining model:
// 512 waves on 1024 SIMDs = 1 wave/SIMD on half the chip, zero TLP -> issue,
// chain stalls, and vmcnt gaps all serialize (~264 cyc/step vs 183 drain).
// R6: 4 threads per trajectory, each redundantly computes the full SEIR step
// (bit-identical) and stores ONE component. 2048 waves = 2/SIMD on the whole
// machine; redundant VALU is free (issue 108 cyc/step < 183 drain), TLP=2
// hides the dependent chain and store retirement.

constexpr int   B_TRAJ  = 32768;
constexpr int   NSTEPS  = 1000;
constexpr float DT      = 0.01f;
constexpr float EPS     = 1e-6f;
constexpr float INV_N   = 1.0f / 10000.0f;   // replaces fdiv (<=1 ulp; thr ~2%)

__global__ __launch_bounds__(256) void seir_sde_kernel(
    const float* __restrict__ beta,
    const float* __restrict__ sigma,
    const float* __restrict__ gamma,
    const float* __restrict__ S0,
    const float* __restrict__ E0,
    const float* __restrict__ I0,
    const float* __restrict__ R0,
    const float4* __restrict__ dW,   // [NSTEPS] x (w0,w1,w2,w3)
    float* __restrict__ out)         // [NSTEPS][4][B_TRAJ]
{
    // One-time LDS stage of all noise, pre-scaled by sqrt(dt). 16 KB/block.
    __shared__ float4 wbuf[NSTEPS];
    const float sdt = 0.1f;                  // sqrt(0.01), exact
    for (int i = threadIdx.x; i < NSTEPS; i += 256) {
        const float4 w = dW[i];
        wbuf[i] = make_float4(w.x * sdt, w.y * sdt, w.z * sdt, 0.0f);
    }

    // Wave w of the block owns component c=w for 64 trajectories; all 4 waves
    // compute the same trajectories redundantly (bit-identical sequences).
    const int lane = threadIdx.x & 63;
    const int c    = threadIdx.x >> 6;       // 0..3 = S,E,I,R
    const int b    = blockIdx.x * 64 + lane;

    const float btn = beta[0] * INV_N;       // hoisted: beta/N
    const float sg  = sigma[0];
    const float gm  = gamma[0];

    float S = S0[b];
    float E = E0[b];
    float I = I0[b];
    float R = R0[b];

    // Wave-uniform component selectors (3 cndmasks per step at store).
    const bool c_hi = (c & 2) != 0;
    const bool c_lo = (c & 1) != 0;

    float* o = out + c * B_TRAJ + b;

    __syncthreads();

    static_assert(NSTEPS % 10 == 0, "unroll tail not handled");
    #pragma unroll 10
    for (int s = 0; s < NSTEPS; ++s) {
        const float4 w = wbuf[s];            // lane-uniform LDS broadcast

        // Clamp at step entry; stored values remain unclamped (matches ref).
        S = fmaxf(S, EPS);
        E = fmaxf(E, EPS);
        I = fmaxf(I, EPS);
        R = fmaxf(R, EPS);

        const float inf_rate = btn * S * I;  // beta*S*I/N
        const float exp_rate = sg * E;
        const float rec_rate = gm * I;

        // Rates strictly positive after clamp: raw sqrt is safe.
        const float n_inf = __builtin_amdgcn_sqrtf(inf_rate);
        const float n_exp = __builtin_amdgcn_sqrtf(exp_rate);
        const float n_rec = __builtin_amdgcn_sqrtf(rec_rate);

        const float a_inf = n_inf * w.x;     // already sqrt(dt)-scaled
        const float a_exp = n_exp * w.y;
        const float a_rec = n_rec * w.z;

        const float Sn = S - inf_rate * DT              - a_inf;
        const float En = E + (inf_rate - exp_rate) * DT + a_inf - a_exp;
        const float In = I + (exp_rate - rec_rate) * DT + a_exp - a_rec;
        const float Rn = R + rec_rate * DT              + a_rec;

        // This wave stores only its component: 64 consecutive dwords (256 B).
        const float lo = c_lo ? En : Sn;
        const float hi = c_lo ? Rn : In;
        const float v  = c_hi ? hi : lo;
        o[0] = v;
        o += 4 * B_TRAJ;

        S = Sn; E = En; I = In; R = Rn;
    }
}

extern "C" void kernel_launch(void* const* d_in, const int* in_sizes, int n_in,
                              void* d_out, int out_size, void* d_ws, size_t ws_size,
                              hipStream_t stream) {
    const float*  beta  = (const float*)d_in[0];
    const float*  sigma = (const float*)d_in[1];
    const float*  gamma = (const float*)d_in[2];
    const float*  S0    = (const float*)d_in[3];
    const float*  E0    = (const float*)d_in[4];
    const float*  I0    = (const float*)d_in[5];
    const float*  R0    = (const float*)d_in[6];
    const float4* dW    = (const float4*)d_in[7];
    float* out = (float*)d_out;

    seir_sde_kernel<<<B_TRAJ / 64, 256, 0, stream>>>(
        beta, sigma, gamma, S0, E0, I0, R0, dW, out);
}

// Round 7
// 97.214 us; speedup vs baseline: 1.5196x; 1.5196x over previous
//
#include <hip/hip_runtime.h>

// SEIR SDE: B=32768 x 1000 steps -> out[step][4][B] f32 = 524 MB (write-bound).
// Evidence through R6: time/step = VALU + ~184cyc, strictly additive -> the
// compute wave stalls in its own store backpressure (vmcnt full at HBM drain
// rate); TLP of identical waves doesn't help (all backpressured in lockstep).
// R7: producer/consumer wave split. Wave0 = compute -> LDS ring (no global
// stores ever). Wave1 = drain: ds_read_b128 (1KB/step contiguous) + ONE
// global_store_dwordx4 per step. Store wave eats all vmcnt waits; compute
// runs free. Double-buffered K=20-step chunks, barrier per chunk (50 total).

constexpr int   B_TRAJ  = 32768;
constexpr int   NSTEPS  = 1000;
constexpr int   K       = 20;            // steps per chunk
constexpr int   NC      = NSTEPS / K;    // 50 chunks
constexpr float DT      = 0.01f;
constexpr float EPS     = 1e-6f;
constexpr float INV_N   = 1.0f / 10000.0f;   // replaces fdiv (<=1 ulp; thr ~2%)

__global__ __launch_bounds__(128) void seir_sde_kernel(
    const float* __restrict__ beta,
    const float* __restrict__ sigma,
    const float* __restrict__ gamma,
    const float* __restrict__ S0,
    const float* __restrict__ E0,
    const float* __restrict__ I0,
    const float* __restrict__ R0,
    const float4* __restrict__ dW,   // [NSTEPS] x (w0,w1,w2,w3)
    float* __restrict__ out)         // [NSTEPS][4][B_TRAJ]
{
    __shared__ float4 wbuf[NSTEPS];          // pre-scaled noise, 16 KB
    __shared__ float  ring[2][K][4][64];     // double-buffered chunk, 40 KB

    const float sdt = 0.1f;                  // sqrt(0.01), exact
    for (int i = threadIdx.x; i < NSTEPS; i += 128) {
        const float4 w = dW[i];
        wbuf[i] = make_float4(w.x * sdt, w.y * sdt, w.z * sdt, 0.0f);
    }

    const int lane = threadIdx.x & 63;
    const int wid  = threadIdx.x >> 6;       // 0 = compute wave, 1 = store wave

    // Compute-wave state (dead registers in the store wave).
    float S = 0.f, E = 0.f, I = 0.f, R = 0.f, btn = 0.f, sg = 0.f, gm = 0.f;
    if (wid == 0) {
        const int b = blockIdx.x * 64 + lane;
        S = S0[b]; E = E0[b]; I = I0[b]; R = R0[b];
        btn = beta[0] * INV_N; sg = sigma[0]; gm = gamma[0];
    }

    // Store-wave addressing: lane l -> component (l>>4), trajectories
    // 4*(l&15)..+3 of this block. One dwordx4 = 4 x 256B segments.
    float* const obase = out + blockIdx.x * 64
                             + (lane >> 4) * B_TRAJ + (lane & 15) * 4;

    __syncthreads();                         // noise staged

    // ---- prologue: compute wave fills chunk 0 into ring[0] ----
    if (wid == 0) {
        #pragma unroll 5
        for (int k = 0; k < K; ++k) {
            const float4 w = wbuf[k];
            S = fmaxf(S, EPS); E = fmaxf(E, EPS);
            I = fmaxf(I, EPS); R = fmaxf(R, EPS);
            const float inf = btn * S * I;
            const float ex  = sg * E;
            const float rc  = gm * I;
            const float ni = __builtin_amdgcn_sqrtf(inf);
            const float ne = __builtin_amdgcn_sqrtf(ex);
            const float nr = __builtin_amdgcn_sqrtf(rc);
            const float ai = ni * w.x, ae = ne * w.y, ar = nr * w.z;
            const float Sn = S - inf * DT             - ai;
            const float En = E + (inf - ex) * DT + ai - ae;
            const float In = I + (ex - rc) * DT  + ae - ar;
            const float Rn = R + rc * DT              + ar;
            ring[0][k][0][lane] = Sn;
            ring[0][k][1][lane] = En;
            ring[0][k][2][lane] = In;
            ring[0][k][3][lane] = Rn;
            S = Sn; E = En; I = In; R = Rn;
        }
    }
    __syncthreads();

    // ---- pipeline: iter c drains chunk c while filling chunk c+1 ----
    for (int c = 0; c < NC; ++c) {
        if (wid == 0) {
            if (c + 1 < NC) {
                const int s0 = (c + 1) * K;
                float (*rw)[4][64] = ring[(c + 1) & 1];
                #pragma unroll 5
                for (int k = 0; k < K; ++k) {
                    const float4 w = wbuf[s0 + k];
                    S = fmaxf(S, EPS); E = fmaxf(E, EPS);
                    I = fmaxf(I, EPS); R = fmaxf(R, EPS);
                    const float inf = btn * S * I;
                    const float ex  = sg * E;
                    const float rc  = gm * I;
                    const float ni = __builtin_amdgcn_sqrtf(inf);
                    const float ne = __builtin_amdgcn_sqrtf(ex);
                    const float nr = __builtin_amdgcn_sqrtf(rc);
                    const float ai = ni * w.x, ae = ne * w.y, ar = nr * w.z;
                    const float Sn = S - inf * DT             - ai;
                    const float En = E + (inf - ex) * DT + ai - ae;
                    const float In = I + (ex - rc) * DT  + ae - ar;
                    const float Rn = R + rc * DT              + ar;
                    rw[k][0][lane] = Sn;
                    rw[k][1][lane] = En;
                    rw[k][2][lane] = In;
                    rw[k][3][lane] = Rn;
                    S = Sn; E = En; I = In; R = Rn;
                }
            }
        } else {
            // Drain chunk c: K x { 1 ds_read_b128 + 1 global_store_dwordx4 }.
            const float4* rd = (const float4*)&ring[c & 1][0][0][0];
            float* o = obase + (size_t)(c * K) * (4 * B_TRAJ);
            #pragma unroll
            for (int k = 0; k < K; ++k) {
                const float4 v = rd[k * 64 + lane];   // contiguous 1KB/step
                *(float4*)o = v;
                o += 4 * B_TRAJ;
            }
        }
        __syncthreads();
    }
}

extern "C" void kernel_launch(void* const* d_in, const int* in_sizes, int n_in,
                              void* d_out, int out_size, void* d_ws, size_t ws_size,
                              hipStream_t stream) {
    const float*  beta  = (const float*)d_in[0];
    const float*  sigma = (const float*)d_in[1];
    const float*  gamma = (const float*)d_in[2];
    const float*  S0    = (const float*)d_in[3];
    const float*  E0    = (const float*)d_in[4];
    const float*  I0    = (const float*)d_in[5];
    const float*  R0    = (const float*)d_in[6];
    const float4* dW    = (const float4*)d_in[7];
    float* out = (float*)d_out;

    seir_sde_kernel<<<B_TRAJ / 64, 128, 0, stream>>>(
        beta, sigma, gamma, S0, E0, I0, R0, dW, out);
}